// Round 3
// baseline (84.965 us; speedup 1.0000x reference)
//
#include <hip/hip_runtime.h>
#include <hip/hip_bf16.h>

#define NUM_RHS_EMB 100000
#define NUM_TYPES   64
#define NUM_LHS_EMB 100000
#define NR 8192   // rhs idxs -> output cols (contiguous out dim)
#define NL 8192   // lhs idxs -> output rows
#define LSE_CHUNKS 25
#define LSE_CHUNK  4000                       // 16 KB per chunk, 16B-aligned
#define LSE_BLOCKS (NUM_TYPES * LSE_CHUNKS)   // 1600
#define ASIDE_BLOCKS (NR / 4)                 // 2048 waves / 4 per block = 512

typedef __attribute__((ext_vector_type(8))) short short8;
typedef __attribute__((ext_vector_type(4))) float f32x4;

__device__ __forceinline__ ushort f2b(float x) {
    unsigned u = __builtin_bit_cast(unsigned, x);
    unsigned r = u + 0x7fffu + ((u >> 16) & 1u);   // RNE-ish
    return (ushort)(r >> 16);
}

// ---------------- K1: fused lse partials + a-side ----------------
__global__ __launch_bounds__(256) void prep1_kernel(
    const float* __restrict__ t, const float* __restrict__ bias, float2* __restrict__ part,
    const float* __restrict__ rts, const int* __restrict__ ridx,
    ushort* __restrict__ ea, float* __restrict__ ma) {
    const int tid = threadIdx.x;
    if (blockIdx.x < LSE_BLOCKS) {
        const int k = blockIdx.x / LSE_CHUNKS;
        const int c = blockIdx.x % LSE_CHUNKS;
        const float4* __restrict__ row = (const float4*)(t + (size_t)k * NUM_LHS_EMB + c * LSE_CHUNK);
        const float4* __restrict__ bb  = (const float4*)(bias + c * LSE_CHUNK);
        __shared__ float red[4];
        const int w = tid >> 6;

        float m = -1e30f;
        for (int j = tid; j < LSE_CHUNK / 4; j += 256) {
            float4 tv = row[j], bv = bb[j];
            m = fmaxf(m, fmaxf(fmaxf(tv.x + bv.x, tv.y + bv.y), fmaxf(tv.z + bv.z, tv.w + bv.w)));
        }
        #pragma unroll
        for (int d = 1; d < 64; d <<= 1) m = fmaxf(m, __shfl_xor(m, d));
        if ((tid & 63) == 0) red[w] = m;
        __syncthreads();
        m = fmaxf(fmaxf(red[0], red[1]), fmaxf(red[2], red[3]));
        __syncthreads();

        float s = 0.f;
        for (int j = tid; j < LSE_CHUNK / 4; j += 256) {
            float4 tv = row[j], bv = bb[j];
            s += expf(tv.x + bv.x - m) + expf(tv.y + bv.y - m)
               + expf(tv.z + bv.z - m) + expf(tv.w + bv.w - m);
        }
        #pragma unroll
        for (int d = 1; d < 64; d <<= 1) s += __shfl_xor(s, d);
        if ((tid & 63) == 0) red[w] = s;
        __syncthreads();
        if (tid == 0) part[blockIdx.x] = make_float2(m, red[0] + red[1] + red[2] + red[3]);
    } else {
        // a-side: wave per r, lane = k
        const int r = (blockIdx.x - LSE_BLOCKS) * 4 + (tid >> 6);
        const int k = tid & 63;
        const float v = rts[(size_t)ridx[r] * 64 + k];
        float m = v;
        #pragma unroll
        for (int d = 1; d < 64; d <<= 1) m = fmaxf(m, __shfl_xor(m, d));
        const float e = expf(v - m);
        float s = e;
        #pragma unroll
        for (int d = 1; d < 64; d <<= 1) s += __shfl_xor(s, d);
        ea[(size_t)r * 64 + k] = f2b(e);
        if (k == 0) ma[r] = -logf(s);
    }
}

// ---------------- K2: b-side with in-block LSE combine ----------------
__global__ __launch_bounds__(256) void bside_kernel(
    const float* __restrict__ t, const float* __restrict__ bias,
    const int* __restrict__ lidx, const float2* __restrict__ part,
    ushort* __restrict__ ebt, float* __restrict__ mb) {
    __shared__ float lse_s[NUM_TYPES];
    const int tid = threadIdx.x;
    if (tid < NUM_TYPES) {
        float2 p[LSE_CHUNKS];
        #pragma unroll
        for (int c = 0; c < LSE_CHUNKS; c++) p[c] = part[tid * LSE_CHUNKS + c];
        float M = -1e30f;
        #pragma unroll
        for (int c = 0; c < LSE_CHUNKS; c++) M = fmaxf(M, p[c].x);
        float S = 0.f;
        #pragma unroll
        for (int c = 0; c < LSE_CHUNKS; c++) S += p[c].y * expf(p[c].x - M);
        lse_s[tid] = M + logf(S);
    }
    __syncthreads();

    const int l = blockIdx.x * 4 + (tid >> 6);
    const int k = tid & 63;
    const int j = lidx[l];
    const float v = t[(size_t)k * NUM_LHS_EMB + j] - lse_s[k];
    float m = v;
    #pragma unroll
    for (int d = 1; d < 64; d <<= 1) m = fmaxf(m, __shfl_xor(m, d));
    ebt[(size_t)l * 64 + k] = f2b(expf(v - m));
    if (k == 0) mb[l] = m + bias[j];
}

// ---------------- K3: out[l][r] = log( ebt[l,:] . ea[r,:] ) + ma[r] + mb[l] ----
// Operands swapped vs r1: A = ea (r rows) so acc reg axis -> r (contiguous in out).
// 128x128 block tile, 64x64 per wave; per-lane f32x4 stores.
__global__ __launch_bounds__(256) void gemm_kernel(
    const ushort* __restrict__ B_ea,   // ea  [NR][64]
    const ushort* __restrict__ A_ebt,  // ebt [NL][64]
    const float* __restrict__ ma, const float* __restrict__ mb,
    float* __restrict__ out) {
    const int bm = blockIdx.x & 63;       // l tile
    const int bn = blockIdx.x >> 6;       // r tile
    const int w = threadIdx.x >> 6, lane = threadIdx.x & 63;
    const int Moff = bm * 128 + (w >> 1) * 64;   // l
    const int Noff = bn * 128 + (w & 1) * 64;    // r
    const int lrow = lane & 15;
    const int lk = (lane >> 4) * 8;
    const int rq = (lane >> 4) * 4;

    f32x4 acc[4][4] = {};   // acc[i][j]: i -> r tile, j -> l tile
    #pragma unroll
    for (int kb = 0; kb < 64; kb += 32) {
        short8 a[4], b[4];
        #pragma unroll
        for (int i = 0; i < 4; i++)
            a[i] = *(const short8*)(B_ea + (size_t)(Noff + i * 16 + lrow) * 64 + kb + lk);
        #pragma unroll
        for (int j = 0; j < 4; j++)
            b[j] = *(const short8*)(A_ebt + (size_t)(Moff + j * 16 + lrow) * 64 + kb + lk);
        #pragma unroll
        for (int i = 0; i < 4; i++)
            #pragma unroll
            for (int j = 0; j < 4; j++)
                acc[i][j] = __builtin_amdgcn_mfma_f32_16x16x32_bf16(a[i], b[j], acc[i][j], 0, 0, 0);
    }

    f32x4 mav[4];
    #pragma unroll
    for (int i = 0; i < 4; i++) mav[i] = *(const f32x4*)(ma + Noff + i * 16 + rq);

    #pragma unroll
    for (int j = 0; j < 4; j++) {
        const int l_out = Moff + j * 16 + lrow;
        const float mbv = mb[l_out];
        float* __restrict__ orow = out + (size_t)l_out * NR + Noff;
        #pragma unroll
        for (int i = 0; i < 4; i++) {
            f32x4 v;
            #pragma unroll
            for (int jr = 0; jr < 4; jr++)
                v[jr] = __logf(acc[i][j][jr]) + mav[i][jr] + mbv;
            *(f32x4*)(orow + i * 16 + rq) = v;
        }
    }
}

extern "C" void kernel_launch(void* const* d_in, const int* in_sizes, int n_in,
                              void* d_out, int out_size, void* d_ws, size_t ws_size,
                              hipStream_t stream) {
    const float* rts  = (const float*)d_in[0];   // [100000, 64]
    const float* tls  = (const float*)d_in[1];   // [64, 100000]
    const float* bias = (const float*)d_in[2];   // [1, 100000]
    const int* ridx   = (const int*)d_in[3];     // [8192]
    const int* lidx   = (const int*)d_in[4];     // [8192]
    float* out = (float*)d_out;                  // [8192, 8192]

    char* ws = (char*)d_ws;
    ushort* ea   = (ushort*)ws;                                  // NR*64 bf16 = 1 MB
    ushort* ebt  = (ushort*)(ws + (size_t)NR * 64 * 2);          // NL*64 bf16 = 1 MB
    float* ma    = (float*)(ws + (size_t)(NR + NL) * 64 * 2);    // NR floats
    float* mb    = (float*)(ws + (size_t)(NR + NL) * 64 * 2 + NR * 4);
    float2* part = (float2*)(ws + (size_t)(NR + NL) * 64 * 2 + (NR + NL) * 4);  // 1600 float2

    prep1_kernel<<<LSE_BLOCKS + ASIDE_BLOCKS, 256, 0, stream>>>(tls, bias, part, rts, ridx, ea, ma);
    bside_kernel<<<NL / 4, 256, 0, stream>>>(tls, bias, lidx, part, ebt, mb);
    gemm_kernel<<<(NL / 128) * (NR / 128), 256, 0, stream>>>(ea, ebt, ma, mb, out);
}